// Round 1
// baseline (2338.330 us; speedup 1.0000x reference)
//
#include <hip/hip_runtime.h>

#define DECAYF 0.8f
#define OMDF   0.2f   // 1 - decay
#define EPSF   1e-5f
#define COMMITF 1.0f

static constexpr int BT = 64;   // rows per block tile
static constexpr int BK = 64;   // codes per block tile
static constexpr int DC = 32;   // d-chunk staged for E
static constexpr int DMAX = 256;

// ---------------- zero accumulators ----------------
__global__ void k_zero(float* __restrict__ p, int n) {
  int i = blockIdx.x * blockDim.x + threadIdx.x;
  int stride = gridDim.x * blockDim.x;
  for (; i < n; i += stride) p[i] = 0.0f;
}

// ---------------- 0.5*||e_k||^2 ----------------
__global__ void k_prep(const float* __restrict__ embed, float* __restrict__ ee, int K, int D) {
  int wave = threadIdx.x >> 6;
  int lane = threadIdx.x & 63;
  int k = blockIdx.x * 4 + wave;
  if (k >= K) return;
  const float* e = embed + (size_t)k * D;
  float s = 0.f;
  for (int d = lane * 4; d < D; d += 256) {
    float4 v = *reinterpret_cast<const float4*>(e + d);
    s += v.x * v.x + v.y * v.y + v.z * v.z + v.w * v.w;
  }
  for (int off = 32; off > 0; off >>= 1) s += __shfl_down(s, off);
  if (lane == 0) ee[k] = 0.5f * s;
}

// ---------------- fused dist + argmax ----------------
// score(t,k) = x_t . e_k - 0.5*||e_k||^2 ; argmax_k with first-index tie-break.
__global__ __launch_bounds__(256) void k_dist(
    const float* __restrict__ x, const float* __restrict__ embed,
    const float* __restrict__ ee, float* __restrict__ ind_f,
    int* __restrict__ idx_out, int T, int K, int D)
{
  __shared__ alignas(16) float Xs[DMAX][BT + 4];  // [d][r]
  __shared__ alignas(16) float Es[DC][BK + 4];    // [d][c]
  const int tid = threadIdx.x;
  const int tx = tid & 15;   // code sub-tile
  const int ty = tid >> 4;   // row sub-tile
  const int row0 = blockIdx.x * BT;

  // Load full X tile (BT x D) transposed into LDS.
  const int DQ = D / 4;
  for (int i = tid; i < BT * DQ; i += 256) {
    int r = i / DQ;
    int dq = i % DQ;
    float4 v = *reinterpret_cast<const float4*>(x + (size_t)(row0 + r) * D + dq * 4);
    Xs[dq * 4 + 0][r] = v.x;
    Xs[dq * 4 + 1][r] = v.y;
    Xs[dq * 4 + 2][r] = v.z;
    Xs[dq * 4 + 3][r] = v.w;
  }

  float best[4];
  int bidx[4];
#pragma unroll
  for (int i = 0; i < 4; ++i) { best[i] = -3.0e38f; bidx[i] = 0; }

  for (int k0 = 0; k0 < K; k0 += BK) {
    float acc[4][4];
#pragma unroll
    for (int i = 0; i < 4; ++i)
#pragma unroll
      for (int j = 0; j < 4; ++j) acc[i][j] = 0.f;

    for (int d0 = 0; d0 < D; d0 += DC) {
      __syncthreads();  // previous chunk's readers done (also covers initial Xs load)
      for (int i = tid; i < BK * (DC / 4); i += 256) {
        int c = i / (DC / 4);
        int dq = i % (DC / 4);
        float4 v = *reinterpret_cast<const float4*>(
            embed + (size_t)(k0 + c) * D + d0 + dq * 4);
        Es[dq * 4 + 0][c] = v.x;
        Es[dq * 4 + 1][c] = v.y;
        Es[dq * 4 + 2][c] = v.z;
        Es[dq * 4 + 3][c] = v.w;
      }
      __syncthreads();
#pragma unroll
      for (int d = 0; d < DC; ++d) {
        float4 xa = *reinterpret_cast<const float4*>(&Xs[d0 + d][ty * 4]);
        float4 eb = *reinterpret_cast<const float4*>(&Es[d][tx * 4]);
        float ax[4] = {xa.x, xa.y, xa.z, xa.w};
        float eb4[4] = {eb.x, eb.y, eb.z, eb.w};
#pragma unroll
        for (int i = 0; i < 4; ++i)
#pragma unroll
          for (int j = 0; j < 4; ++j) acc[i][j] += ax[i] * eb4[j];
      }
    }

    // per-tile argmax epilogue
#pragma unroll
    for (int i = 0; i < 4; ++i) {
      float m = -3.0e38f;
      int mi = 0;
#pragma unroll
      for (int j = 0; j < 4; ++j) {
        int c = k0 + tx * 4 + j;
        float s = acc[i][j] - ee[c];
        if (s > m) { m = s; mi = c; }
      }
#pragma unroll
      for (int off = 1; off < 16; off <<= 1) {
        float om = __shfl_xor(m, off);
        int oi = __shfl_xor(mi, off);
        if (om > m || (om == m && oi < mi)) { m = om; mi = oi; }
      }
      if (m > best[i]) { best[i] = m; bidx[i] = mi; }  // strict > keeps earliest k
    }
  }

  if (tx == 0) {
#pragma unroll
    for (int i = 0; i < 4; ++i) {
      int row = row0 + ty * 4 + i;
      idx_out[row] = bidx[i];
      ind_f[row] = (float)bidx[i];
    }
  }
}

// ---------------- gather + commit-loss partials + scatter stats ----------------
__global__ void k_gather(const float* __restrict__ x, const float* __restrict__ embed,
                         const int* __restrict__ idx, float* __restrict__ quant,
                         float* __restrict__ bins, float* __restrict__ esum,
                         float* __restrict__ lslots, int T, int D)
{
  int wave = threadIdx.x >> 6;
  int lane = threadIdx.x & 63;
  int row = blockIdx.x * 4 + wave;
  if (row >= T) return;
  int k = idx[row];
  const float* xr = x + (size_t)row * D;
  const float* er = embed + (size_t)k * D;
  float* qr = quant + (size_t)row * D;
  float* esr = esum + (size_t)k * D;
  float lsum = 0.f;
  for (int d = lane * 4; d < D; d += 256) {
    float4 xv = *reinterpret_cast<const float4*>(xr + d);
    float4 ev = *reinterpret_cast<const float4*>(er + d);
    *reinterpret_cast<float4*>(qr + d) = ev;
    float dx = ev.x - xv.x, dy = ev.y - xv.y, dz = ev.z - xv.z, dw = ev.w - xv.w;
    lsum += dx * dx + dy * dy + dz * dz + dw * dw;
    atomicAdd(esr + d + 0, xv.x);
    atomicAdd(esr + d + 1, xv.y);
    atomicAdd(esr + d + 2, xv.z);
    atomicAdd(esr + d + 3, xv.w);
  }
  for (int off = 32; off > 0; off >>= 1) lsum += __shfl_down(lsum, off);
  if (lane == 0) {
    atomicAdd(&bins[k], 1.0f);
    atomicAdd(&lslots[row & 255], lsum);
  }
}

// ---------------- new_cluster_size + total ----------------
__global__ void k_ema1(const float* __restrict__ cs, const float* __restrict__ bins,
                       float* __restrict__ ncs, float* __restrict__ total_acc, int K)
{
  int k = blockIdx.x * 256 + threadIdx.x;
  float v = 0.f;
  if (k < K) {
    v = cs[k] * DECAYF + OMDF * bins[k];
    ncs[k] = v;  // scalar store: output region may be 4B-aligned only
  }
  for (int off = 32; off > 0; off >>= 1) v += __shfl_down(v, off);
  __shared__ float s4[4];
  if ((threadIdx.x & 63) == 0) s4[threadIdx.x >> 6] = v;
  __syncthreads();
  if (threadIdx.x == 0) atomicAdd(total_acc, s4[0] + s4[1] + s4[2] + s4[3]);
}

// ---------------- new_embed_avg + new_embed ----------------
__global__ void k_ema2(const float* __restrict__ ea, const float* __restrict__ esum,
                       const float* __restrict__ ncs, const float* __restrict__ total_acc,
                       float* __restrict__ ne, float* __restrict__ nea, int K, int D)
{
  int gid = blockIdx.x * 256 + threadIdx.x;
  if (gid >= K * D) return;
  int k = gid / D;
  float total = *total_acc;
  float c = ncs[k];
  float sm = (c + EPSF) / (total + (float)K * EPSF) * total;
  float v = ea[gid] * DECAYF + OMDF * esum[gid];
  nea[gid] = v;   // scalar stores: odd float offsets in d_out
  ne[gid] = v / sm;
}

// ---------------- finalize commit loss ----------------
__global__ void k_loss(const float* __restrict__ lslots, float* __restrict__ out_loss,
                       float scale)
{
  int tid = threadIdx.x;
  float v = lslots[tid];
  for (int off = 32; off > 0; off >>= 1) v += __shfl_down(v, off);
  __shared__ float s4[4];
  if ((tid & 63) == 0) s4[tid >> 6] = v;
  __syncthreads();
  if (tid == 0) out_loss[0] = (s4[0] + s4[1] + s4[2] + s4[3]) * scale;
}

extern "C" void kernel_launch(void* const* d_in, const int* in_sizes, int n_in,
                              void* d_out, int out_size, void* d_ws, size_t ws_size,
                              hipStream_t stream)
{
  const float* x     = (const float*)d_in[0];
  const float* embed = (const float*)d_in[1];
  const float* cs    = (const float*)d_in[2];
  const float* ea    = (const float*)d_in[3];
  const int K = in_sizes[2];            // 8192
  const int D = in_sizes[1] / K;        // 256
  const int T = in_sizes[0] / D;        // 32768

  float* out   = (float*)d_out;
  float* o_q   = out;                        // T*D
  float* o_ind = out + (size_t)T * D;        // T
  float* o_ls  = o_ind + T;                  // 1
  float* o_ne  = o_ls + 1;                   // K*D (odd float offset!)
  float* o_ncs = o_ne + (size_t)K * D;       // K
  float* o_nea = o_ncs + K;                  // K*D

  float* w      = (float*)d_ws;
  float* ee     = w;                          // K
  int*   idx    = (int*)(w + K);              // T
  float* bins   = w + K + T;                  // K   } zeroed region
  float* esum   = bins + K;                   // K*D }
  float* lslots = esum + (size_t)K * D;       // 256 }
  float* total  = lslots + 256;               // 1   }
  int zero_n = K + K * D + 256 + 1;

  k_zero<<<2048, 256, 0, stream>>>(bins, zero_n);
  k_prep<<<(K + 3) / 4, 256, 0, stream>>>(embed, ee, K, D);
  k_dist<<<T / BT, 256, 0, stream>>>(x, embed, ee, o_ind, idx, T, K, D);
  k_gather<<<(T + 3) / 4, 256, 0, stream>>>(x, embed, idx, o_q, bins, esum, lslots, T, D);
  k_ema1<<<(K + 255) / 256, 256, 0, stream>>>(cs, bins, o_ncs, total, K);
  k_ema2<<<(K * D + 255) / 256, 256, 0, stream>>>(ea, esum, o_ncs, total, o_ne, o_nea, K, D);
  k_loss<<<1, 256, 0, stream>>>(lslots, o_ls, COMMITF / ((float)T * (float)D));
}

// Round 5
// 896.018 us; speedup vs baseline: 2.6097x; 2.6097x over previous
//
#include <hip/hip_runtime.h>

#define DECAYF 0.8f
#define OMDF   0.2f
#define EPSF   1e-5f
#define COMMITF 1.0f
#define MARGINF 0.02f

typedef short s8v __attribute__((ext_vector_type(8)));
typedef float f4v __attribute__((ext_vector_type(4)));
typedef unsigned short u16;

__device__ inline u16 f2bf(float f) {
  unsigned u = __float_as_uint(f);
  return (u16)((u + 0x7FFFu + ((u >> 16) & 1u)) >> 16);
}
__device__ inline float bf2f(u16 h) { return __uint_as_float(((unsigned)h) << 16); }

__device__ inline void gload_lds16(const void* g, void* l) {
  __builtin_amdgcn_global_load_lds(
      (const __attribute__((address_space(1))) unsigned int*)g,
      (__attribute__((address_space(3))) unsigned int*)l, 16, 0, 0);
}

// ---------------- zero accumulators ----------------
__global__ void k_zero(float* __restrict__ p, int n) {
  int i = blockIdx.x * blockDim.x + threadIdx.x;
  int stride = gridDim.x * blockDim.x;
  for (; i < n; i += stride) p[i] = 0.0f;
}

// ---------------- embed -> hi/lo bf16, tile-contiguous, pre-swizzled ----------------
// Tile tt (64 codes): 64KB at Ews + tt*65536. First 32KB = hi, next 32KB = lo.
// value(c,d) at byte c*512 + ((d*2) ^ ((c&7)<<4)).
__global__ void k_conv(const float* __restrict__ embed, char* __restrict__ Ews, int K, int D) {
  int gid = blockIdx.x * 256 + threadIdx.x;
  if (gid >= K * (D / 8)) return;
  int k = gid >> 5;
  int dchunk = gid & 31;
  int d0 = dchunk * 8;
  const float* ep = embed + (size_t)k * D + d0;
  float4 v0 = *(const float4*)(ep);
  float4 v1 = *(const float4*)(ep + 4);
  float f[8] = {v0.x, v0.y, v0.z, v0.w, v1.x, v1.y, v1.z, v1.w};
  s8v h, l;
#pragma unroll
  for (int e = 0; e < 8; ++e) {
    u16 hb = f2bf(f[e]);
    h[e] = (short)hb;
    l[e] = (short)f2bf(f[e] - bf2f(hb));
  }
  int tt = k >> 6;
  int c = k & 63;
  int byteoff = c * 512 + ((d0 * 2) ^ ((c & 7) << 4));
  char* base = Ews + (size_t)tt * 65536 + byteoff;
  *(s8v*)(base) = h;
  *(s8v*)(base + 32768) = l;
}

// ---------------- 0.5*||e_k||^2 ----------------
__global__ void k_prep(const float* __restrict__ embed, float* __restrict__ ee, int K, int D) {
  int wave = threadIdx.x >> 6;
  int lane = threadIdx.x & 63;
  int k = blockIdx.x * 4 + wave;
  if (k >= K) return;
  const float* e = embed + (size_t)k * D;
  float s = 0.f;
  for (int d = lane * 4; d < D; d += 256) {
    float4 v = *reinterpret_cast<const float4*>(e + d);
    s += v.x * v.x + v.y * v.y + v.z * v.z + v.w * v.w;
  }
  for (int off = 32; off > 0; off >>= 1) s += __shfl_down(s, off);
  if (lane == 0) ee[k] = 0.5f * s;
}

// ---------------- fused MFMA dist + argmax (+ near-tie flagging) ----------------
__global__ __launch_bounds__(512, 2) void k_dist(
    const float* __restrict__ x, const char* __restrict__ Ews,
    const float* __restrict__ ee, float* __restrict__ ind_f,
    int* __restrict__ idx_out, int* __restrict__ wl, int* __restrict__ cnt,
    int T, int K)
{
  extern __shared__ char lds[];   // 2 x 65536
  const int tid = threadIdx.x;
  const int w = tid >> 6, lane = tid & 63;
  const int l15 = lane & 15, lk = lane >> 4;
  const int rgrp = w >> 1, ch = w & 1;
  const int row0 = blockIdx.x * 128 + rgrp * 32;
  const int NT = K / 64;

  // X fragments (hi/lo bf16): 2 rowfrags x 8 ksteps
  s8v xh[2][8], xl[2][8];
#pragma unroll
  for (int rf = 0; rf < 2; ++rf) {
    const float* xp = x + (size_t)(row0 + rf * 16 + l15) * 256 + lk * 8;
#pragma unroll
    for (int ks = 0; ks < 8; ++ks) {
      float4 v0 = *(const float4*)(xp + ks * 32);
      float4 v1 = *(const float4*)(xp + ks * 32 + 4);
      float f[8] = {v0.x, v0.y, v0.z, v0.w, v1.x, v1.y, v1.z, v1.w};
      s8v h, l;
#pragma unroll
      for (int e = 0; e < 8; ++e) {
        u16 hb = f2bf(f[e]);
        h[e] = (short)hb;
        l[e] = (short)f2bf(f[e] - bf2f(hb));
      }
      xh[rf][ks] = h;
      xl[rf][ks] = l;
    }
  }

  float best[2][4], bst2[2][4];
  int bidx[2][4];
#pragma unroll
  for (int rf = 0; rf < 2; ++rf)
#pragma unroll
    for (int i = 0; i < 4; ++i) { best[rf][i] = -3.0e38f; bst2[rf][i] = -3.0e38f; bidx[rf][i] = 0; }

  // prologue: stage tile 0
  {
    const char* src = Ews + (size_t)w * 8192 + lane * 16;
    char* dst = lds + w * 8192;
#pragma unroll
    for (int q = 0; q < 8; ++q)
      gload_lds16(src + q * 1024, dst + q * 1024);
  }
  __syncthreads();

  const int swz = (l15 & 7) << 4;

  for (int tt = 0; tt < NT; ++tt) {
    const char* cb = lds + (tt & 1) * 65536;
    if (tt + 1 < NT) {
      const char* src = Ews + (size_t)(tt + 1) * 65536 + w * 8192 + lane * 16;
      char* dst = lds + ((tt + 1) & 1) * 65536 + w * 8192;
#pragma unroll
      for (int q = 0; q < 8; ++q)
        gload_lds16(src + q * 1024, dst + q * 1024);
    }

    const int k0 = tt * 64;
    const int code0 = k0 + ch * 32 + l15;
    const float e0 = ee[code0];
    const float e1 = ee[code0 + 16];
    f4v acc[2][2];
#pragma unroll
    for (int rf = 0; rf < 2; ++rf) {
      acc[rf][0] = (f4v){-e0, -e0, -e0, -e0};
      acc[rf][1] = (f4v){-e1, -e1, -e1, -e1};
    }

    const int rowbyte0 = (ch * 32 + l15) * 512;
#pragma unroll
    for (int ks = 0; ks < 8; ++ks) {
      const int dbyte = (ks * 64 + lk * 16) ^ swz;
      const int b0 = rowbyte0 + dbyte;
      const int b1 = b0 + 16 * 512;
      s8v bh0 = *(const s8v*)(cb + b0);
      s8v bl0 = *(const s8v*)(cb + 32768 + b0);
      s8v bh1 = *(const s8v*)(cb + b1);
      s8v bl1 = *(const s8v*)(cb + 32768 + b1);
#pragma unroll
      for (int rf = 0; rf < 2; ++rf) {
        acc[rf][0] = __builtin_amdgcn_mfma_f32_16x16x32_bf16(xh[rf][ks], bh0, acc[rf][0], 0, 0, 0);
        acc[rf][0] = __builtin_amdgcn_mfma_f32_16x16x32_bf16(xl[rf][ks], bh0, acc[rf][0], 0, 0, 0);
        acc[rf][0] = __builtin_amdgcn_mfma_f32_16x16x32_bf16(xh[rf][ks], bl0, acc[rf][0], 0, 0, 0);
        acc[rf][1] = __builtin_amdgcn_mfma_f32_16x16x32_bf16(xh[rf][ks], bh1, acc[rf][1], 0, 0, 0);
        acc[rf][1] = __builtin_amdgcn_mfma_f32_16x16x32_bf16(xl[rf][ks], bh1, acc[rf][1], 0, 0, 0);
        acc[rf][1] = __builtin_amdgcn_mfma_f32_16x16x32_bf16(xh[rf][ks], bl1, acc[rf][1], 0, 0, 0);
      }
    }

    // running top-2 (ascending code order; strict > keeps first index)
#pragma unroll
    for (int rf = 0; rf < 2; ++rf)
#pragma unroll
      for (int cf = 0; cf < 2; ++cf) {
        const int code = k0 + ch * 32 + cf * 16 + l15;
#pragma unroll
        for (int i = 0; i < 4; ++i) {
          float s = acc[rf][cf][i];
          if (s > best[rf][i]) { bst2[rf][i] = best[rf][i]; best[rf][i] = s; bidx[rf][i] = code; }
          else if (s > bst2[rf][i]) { bst2[rf][i] = s; }
        }
      }

    __syncthreads();
  }

  // reduce top-2 across the 16 column-lanes of each lk-group
#pragma unroll
  for (int rf = 0; rf < 2; ++rf)
#pragma unroll
    for (int i = 0; i < 4; ++i) {
      float s = best[rf][i], s2 = bst2[rf][i];
      int mi = bidx[rf][i];
#pragma unroll
      for (int off = 1; off < 16; off <<= 1) {
        float os = __shfl_xor(s, off);
        float os2 = __shfl_xor(s2, off);
        int oi = __shfl_xor(mi, off);
        if (os > s || (os == s && oi < mi)) {
          s2 = fmaxf(s, os2);
          s = os; mi = oi;
        } else {
          s2 = fmaxf(s2, os);
        }
      }
      best[rf][i] = s; bst2[rf][i] = s2; bidx[rf][i] = mi;
    }

  // ---- cross-ch merge via LDS (tile buffers dead after final barrier) ----
  float* S  = (float*)lds;        // 256 entries
  float* S2 = S + 256;            // 256
  int*   MI = (int*)(S2 + 256);   // 256
  if (l15 == 0) {
#pragma unroll
    for (int rf = 0; rf < 2; ++rf)
#pragma unroll
      for (int i = 0; i < 4; ++i) {
        int rl = rf * 16 + lk * 4 + i;
        int a = rgrp * 64 + ch * 32 + rl;
        S[a]  = best[rf][i];
        S2[a] = bst2[rf][i];
        MI[a] = bidx[rf][i];
      }
  }
  __syncthreads();
  if (ch == 0 && lane < 32) {
    int a0 = rgrp * 64 + lane;
    float sA = S[a0],      s2A = S2[a0];      int miA = MI[a0];
    float sB = S[a0 + 32], s2B = S2[a0 + 32]; int miB = MI[a0 + 32];
    float s, s2; int mi;
    if (sB > sA || (sB == sA && miB < miA)) { s = sB; mi = miB; s2 = fmaxf(sA, s2B); }
    else                                    { s = sA; mi = miA; s2 = fmaxf(s2A, sB); }
    int row = row0 + lane;
    idx_out[row] = mi;
    ind_f[row] = (float)mi;
    if (s - s2 < MARGINF) {
      int slot = atomicAdd(cnt, 1);
      wl[slot] = row;
    }
  }
}

// ---------------- exact fp32 rescore for near-tie rows ----------------
// Sequential fmaf chain over d ascending + single -ee subtract: bit-matches
// the round-1 (all-fp32, passing) formula.
__global__ __launch_bounds__(256) void k_fix(
    const float* __restrict__ x, const float* __restrict__ embed,
    const float* __restrict__ ee, const int* __restrict__ wl,
    const int* __restrict__ cnt, float* __restrict__ ind_f,
    int* __restrict__ idx_out, int K, int D)
{
  __shared__ float Xs[256];
  __shared__ float bv[256];
  __shared__ int bi[256];
  const int t = threadIdx.x;
  const int n = *cnt;
  for (int it = blockIdx.x; it < n; it += gridDim.x) {
    __syncthreads();   // protect Xs/bv/bi reuse
    int row = wl[it];
    Xs[t] = x[(size_t)row * D + t];
    __syncthreads();
    float best = -3.0e38f;
    int bidx = 0;
    for (int c0 = 0; c0 < K; c0 += 256) {
      int c = c0 + t;
      const float* er = embed + (size_t)c * D;
      float s = 0.f;
      for (int d = 0; d < D; d += 4) {
        float4 e4 = *(const float4*)(er + d);
        s = fmaf(Xs[d + 0], e4.x, s);
        s = fmaf(Xs[d + 1], e4.y, s);
        s = fmaf(Xs[d + 2], e4.z, s);
        s = fmaf(Xs[d + 3], e4.w, s);
      }
      s -= ee[c];
      if (s > best) { best = s; bidx = c; }
    }
    bv[t] = best; bi[t] = bidx;
    __syncthreads();
    for (int sh = 128; sh > 0; sh >>= 1) {
      if (t < sh) {
        if (bv[t + sh] > bv[t] || (bv[t + sh] == bv[t] && bi[t + sh] < bi[t])) {
          bv[t] = bv[t + sh]; bi[t] = bi[t + sh];
        }
      }
      __syncthreads();
    }
    if (t == 0) {
      idx_out[row] = bi[0];
      ind_f[row] = (float)bi[0];
    }
  }
}

// ---------------- gather + commit-loss partials + scatter stats ----------------
__global__ void k_gather(const float* __restrict__ x, const float* __restrict__ embed,
                         const int* __restrict__ idx, float* __restrict__ quant,
                         float* __restrict__ bins, float* __restrict__ esum,
                         float* __restrict__ lslots, int T, int D)
{
  int wave = threadIdx.x >> 6;
  int lane = threadIdx.x & 63;
  int row = blockIdx.x * 4 + wave;
  if (row >= T) return;
  int k = idx[row];
  const float* xr = x + (size_t)row * D;
  const float* er = embed + (size_t)k * D;
  float* qr = quant + (size_t)row * D;
  float* esr = esum + (size_t)k * D;
  float lsum = 0.f;
  for (int d = lane * 4; d < D; d += 256) {
    float4 xv = *reinterpret_cast<const float4*>(xr + d);
    float4 ev = *reinterpret_cast<const float4*>(er + d);
    *reinterpret_cast<float4*>(qr + d) = ev;
    float dx = ev.x - xv.x, dy = ev.y - xv.y, dz = ev.z - xv.z, dw = ev.w - xv.w;
    lsum += dx * dx + dy * dy + dz * dz + dw * dw;
    atomicAdd(esr + d + 0, xv.x);
    atomicAdd(esr + d + 1, xv.y);
    atomicAdd(esr + d + 2, xv.z);
    atomicAdd(esr + d + 3, xv.w);
  }
  for (int off = 32; off > 0; off >>= 1) lsum += __shfl_down(lsum, off);
  if (lane == 0) {
    atomicAdd(&bins[k], 1.0f);
    atomicAdd(&lslots[row & 255], lsum);
  }
}

// ---------------- new_cluster_size + total ----------------
__global__ void k_ema1(const float* __restrict__ cs, const float* __restrict__ bins,
                       float* __restrict__ ncs, float* __restrict__ total_acc, int K)
{
  int k = blockIdx.x * 256 + threadIdx.x;
  float v = 0.f;
  if (k < K) {
    v = cs[k] * DECAYF + OMDF * bins[k];
    ncs[k] = v;
  }
  for (int off = 32; off > 0; off >>= 1) v += __shfl_down(v, off);
  __shared__ float s4[4];
  if ((threadIdx.x & 63) == 0) s4[threadIdx.x >> 6] = v;
  __syncthreads();
  if (threadIdx.x == 0) atomicAdd(total_acc, s4[0] + s4[1] + s4[2] + s4[3]);
}

// ---------------- new_embed_avg + new_embed ----------------
__global__ void k_ema2(const float* __restrict__ ea, const float* __restrict__ esum,
                       const float* __restrict__ ncs, const float* __restrict__ total_acc,
                       float* __restrict__ ne, float* __restrict__ nea, int K, int D)
{
  int gid = blockIdx.x * 256 + threadIdx.x;
  if (gid >= K * D) return;
  int k = gid / D;
  float total = *total_acc;
  float c = ncs[k];
  float sm = (c + EPSF) / (total + (float)K * EPSF) * total;
  float v = ea[gid] * DECAYF + OMDF * esum[gid];
  nea[gid] = v;
  ne[gid] = v / sm;
}

// ---------------- finalize commit loss ----------------
__global__ void k_loss(const float* __restrict__ lslots, float* __restrict__ out_loss,
                       float scale)
{
  int tid = threadIdx.x;
  float v = lslots[tid];
  for (int off = 32; off > 0; off >>= 1) v += __shfl_down(v, off);
  __shared__ float s4[4];
  if ((tid & 63) == 0) s4[tid >> 6] = v;
  __syncthreads();
  if (tid == 0) out_loss[0] = (s4[0] + s4[1] + s4[2] + s4[3]) * scale;
}

extern "C" void kernel_launch(void* const* d_in, const int* in_sizes, int n_in,
                              void* d_out, int out_size, void* d_ws, size_t ws_size,
                              hipStream_t stream)
{
  const float* x     = (const float*)d_in[0];
  const float* embed = (const float*)d_in[1];
  const float* cs    = (const float*)d_in[2];
  const float* ea    = (const float*)d_in[3];
  const int K = in_sizes[2];            // 8192
  const int D = in_sizes[1] / K;        // 256
  const int T = in_sizes[0] / D;        // 32768

  float* out   = (float*)d_out;
  float* o_q   = out;                        // T*D
  float* o_ind = out + (size_t)T * D;        // T
  float* o_ls  = o_ind + T;                  // 1
  float* o_ne  = o_ls + 1;                   // K*D
  float* o_ncs = o_ne + (size_t)K * D;       // K
  float* o_nea = o_ncs + K;                  // K*D

  float* w      = (float*)d_ws;
  float* ee     = w;                          // K
  int*   idx    = (int*)(w + K);              // T
  int*   wl     = (int*)(w + K + T);          // T
  float* bins   = w + K + 2 * T;              // K   } zeroed
  float* esum   = bins + K;                   // K*D }
  float* lslots = esum + (size_t)K * D;       // 256 }
  float* total  = lslots + 256;               // 1   }
  int*   cnt    = (int*)(total + 1);          // 1   }
  int zero_n = K + K * D + 256 + 2;
  size_t ews_off = ((size_t)(K + 2 * T + K + (size_t)K * D + 256 + 2) + 63) & ~(size_t)63;
  char* Ews = (char*)(w + ews_off);           // K/64 tiles x 64KB = 8MB

  k_zero<<<2048, 256, 0, stream>>>(bins, zero_n);
  k_conv<<<(K * (D / 8) + 255) / 256, 256, 0, stream>>>(embed, Ews, K, D);
  k_prep<<<(K + 3) / 4, 256, 0, stream>>>(embed, ee, K, D);
  k_dist<<<T / 128, 512, 131072, stream>>>(x, Ews, ee, o_ind, idx, wl, cnt, T, K);
  k_fix<<<256, 256, 0, stream>>>(x, embed, ee, wl, cnt, o_ind, idx, K, D);
  k_gather<<<(T + 3) / 4, 256, 0, stream>>>(x, embed, idx, o_q, bins, esum, lslots, T, D);
  k_ema1<<<(K + 255) / 256, 256, 0, stream>>>(cs, bins, o_ncs, total, K);
  k_ema2<<<(K * D + 255) / 256, 256, 0, stream>>>(ea, esum, o_ncs, total, o_ne, o_nea, K, D);
  k_loss<<<1, 256, 0, stream>>>(lslots, o_ls, COMMITF / ((float)T * (float)D));
}